// Round 7
// baseline (250.347 us; speedup 1.0000x reference)
//
#include <hip/hip_runtime.h>
#include <hip/hip_bf16.h>

// Problem constants (B,S,E,H,D) = (4,2048,1024,16,64)
#define PB 4
#define PS 2048
#define PE 1024
#define PH 16
#define PD 64

typedef __attribute__((ext_vector_type(8))) short bf16x8;
typedef __attribute__((ext_vector_type(4))) float f32x4;
typedef __attribute__((ext_vector_type(16))) float f32x16;
typedef const __attribute__((address_space(1))) unsigned int* gas_t;
typedef __attribute__((address_space(3))) unsigned int* las_t;

__device__ __forceinline__ unsigned short f2bf(float f) {
  union { float f; unsigned int u; } v;
  v.f = f;
  unsigned int u = v.u;
  u += 0x7fffu + ((u >> 16) & 1u);  // RNE
  return (unsigned short)(u >> 16);
}

__device__ __forceinline__ f32x4 mfma16(bf16x8 a, bf16x8 b, f32x4 c) {
  return __builtin_amdgcn_mfma_f32_16x16x32_bf16(a, b, c, 0, 0, 0);
}

__device__ __forceinline__ f32x16 mfma32(bf16x8 a, bf16x8 b, f32x16 c) {
  return __builtin_amdgcn_mfma_f32_32x32x16_bf16(a, b, c, 0, 0, 0);
}

// ---------------- fp32 -> bf16 conversion (x, Wk, Wq, Wo fused) --------------
#define CVT_GROUPS ((PB * PS * PE + 3 * PE * PE) / 4)
#define CVT_BLOCKS (CVT_GROUPS / 256)   // 11264
__global__ __launch_bounds__(256) void cvt_kernel(
    const float* __restrict__ x, const float* __restrict__ wk,
    const float* __restrict__ wq, const float* __restrict__ wo,
    unsigned short* __restrict__ xb, unsigned short* __restrict__ wkb,
    unsigned short* __restrict__ wqb, unsigned short* __restrict__ wob) {
  const long long NX = (long long)PB * PS * PE;   // 8388608
  const long long NW = (long long)PE * PE;        // 1048576
  long long i = ((long long)blockIdx.x * 256 + threadIdx.x) * 4;
  const float* src;
  unsigned short* dst;
  long long off;
  if (i < NX)               { src = x;  dst = xb;  off = i; }
  else if (i < NX + NW)     { src = wk; dst = wkb; off = i - NX; }
  else if (i < NX + 2 * NW) { src = wq; dst = wqb; off = i - NX - NW; }
  else                      { src = wo; dst = wob; off = i - NX - 2 * NW; }
  float4 v = *(const float4*)(src + off);
  ushort4 o;
  o.x = f2bf(v.x); o.y = f2bf(v.y); o.z = f2bf(v.z); o.w = f2bf(v.w);
  *(ushort4*)(dst + off) = o;
}

// ---------------- Q / K NT GEMM, split by blockIdx.z -----------------------
// (unchanged from R5 — fell out of top-5 at 4 blocks/CU)
__global__ __launch_bounds__(256) void gemm_qknt(
    const unsigned short* __restrict__ A, const unsigned short* __restrict__ Bq,
    const unsigned short* __restrict__ Bk,
    unsigned short* __restrict__ QT, unsigned short* __restrict__ Kb) {
  const int K = PE, N = PE;
  __shared__ __attribute__((aligned(16))) unsigned short As[128 * 64];
  __shared__ __attribute__((aligned(16))) unsigned short Bs[128 * 64];
  const int tid = threadIdx.x;
  const int wave = tid >> 6, lane = tid & 63;
  const int quad = lane >> 4, ln = lane & 15;
  const int m0 = blockIdx.y * 128, n0 = blockIdx.x * 128;
  const int wm = (wave >> 1) * 64, wn = (wave & 1) * 64;
  const int isK = blockIdx.z;
  const unsigned short* __restrict__ Bsrc = isK ? Bk : Bq;

  f32x4 acc[4][4];
#pragma unroll
  for (int i = 0; i < 4; ++i)
#pragma unroll
    for (int j = 0; j < 4; ++j)
#pragma unroll
      for (int r = 0; r < 4; ++r) acc[i][j][r] = 0.f;

  for (int k0 = 0; k0 < K; k0 += 64) {
#pragma unroll
    for (int it = 0; it < 4; ++it) {
      const int idx = it * 256 + tid;
      const int row = idx >> 3, ch = idx & 7;
      const int gch = ch ^ (row & 7);
      __builtin_amdgcn_global_load_lds(
          (gas_t)(const void*)(A + (size_t)(m0 + row) * K + k0 + gch * 8),
          (las_t)(void*)((char*)As + idx * 16), 16, 0, 0);
      __builtin_amdgcn_global_load_lds(
          (gas_t)(const void*)(Bsrc + (size_t)(n0 + row) * K + k0 + gch * 8),
          (las_t)(void*)((char*)Bs + idx * 16), 16, 0, 0);
    }
    __syncthreads();
#pragma unroll
    for (int kc = 0; kc < 2; ++kc) {
      bf16x8 af[4], bfr[4];
#pragma unroll
      for (int t = 0; t < 4; ++t) {
        const int ra = wm + t * 16 + ln;
        const int rb = wn + t * 16 + ln;
        af[t]  = *(const bf16x8*)(As + ra * 64 + ((kc * 4 + quad) ^ (ra & 7)) * 8);
        bfr[t] = *(const bf16x8*)(Bs + rb * 64 + ((kc * 4 + quad) ^ (rb & 7)) * 8);
      }
      if (!isK) {
#pragma unroll
        for (int mt = 0; mt < 4; ++mt)
#pragma unroll
          for (int nt = 0; nt < 4; ++nt)
            acc[mt][nt] = mfma16(af[mt], bfr[nt], acc[mt][nt]);
      } else {
#pragma unroll
        for (int mt = 0; mt < 4; ++mt)
#pragma unroll
          for (int nt = 0; nt < 4; ++nt)
            acc[mt][nt] = mfma16(bfr[nt], af[mt], acc[mt][nt]);  // swapped
      }
    }
    __syncthreads();
  }

  const float CEXP = 0.045084220f;  // log2(e)/32 folded into K
  if (!isK) {
#pragma unroll
    for (int mt = 0; mt < 4; ++mt)
#pragma unroll
      for (int nt = 0; nt < 4; ++nt) {
        const int row = m0 + wm + mt * 16 + quad * 4;  // token (+r)
        const int col = n0 + wn + nt * 16 + ln;        // feature
        const int b = row >> 11, s = row & 2047;
        const int h = col >> 6, d = col & 63;
        ushort4 ov;
        ov.x = f2bf(acc[mt][nt][0]); ov.y = f2bf(acc[mt][nt][1]);
        ov.z = f2bf(acc[mt][nt][2]); ov.w = f2bf(acc[mt][nt][3]);
        *(ushort4*)(QT + (((size_t)(b * PH + h) * PD + d) * PS + s)) = ov;
      }
  } else {
#pragma unroll
    for (int mt = 0; mt < 4; ++mt)
#pragma unroll
      for (int nt = 0; nt < 4; ++nt) {
        const int krow = m0 + wm + mt * 16 + ln;        // token
        const int kcol = n0 + wn + nt * 16 + quad * 4;  // feature base
        ushort4 kv;
        kv.x = f2bf(acc[mt][nt][0] * CEXP); kv.y = f2bf(acc[mt][nt][1] * CEXP);
        kv.z = f2bf(acc[mt][nt][2] * CEXP); kv.w = f2bf(acc[mt][nt][3] * CEXP);
        *(ushort4*)(Kb + (size_t)krow * N + kcol) = kv;
      }
  }
}

// ---------------- out-projection NT GEMM: C = A * Wo^T + bo (fp32) ----------
// (unchanged from R5)
__global__ __launch_bounds__(256) void gemm_out(
    const unsigned short* __restrict__ A, const unsigned short* __restrict__ Bm,
    const float* __restrict__ bias, float* __restrict__ Cf) {
  const int K = PE, N = PE;
  __shared__ __attribute__((aligned(16))) unsigned short As[64 * 64];
  __shared__ __attribute__((aligned(16))) unsigned short Bs[128 * 64];
  const int tid = threadIdx.x;
  const int wave = tid >> 6, lane = tid & 63;
  const int quad = lane >> 4, ln = lane & 15;
  const int m0 = blockIdx.y * 64, n0 = blockIdx.x * 128;
  const int wm = (wave >> 1) * 32, wn = (wave & 1) * 64;

  f32x4 acc[2][4];
#pragma unroll
  for (int i = 0; i < 2; ++i)
#pragma unroll
    for (int j = 0; j < 4; ++j)
#pragma unroll
      for (int r = 0; r < 4; ++r) acc[i][j][r] = 0.f;

  for (int k0 = 0; k0 < K; k0 += 64) {
#pragma unroll
    for (int it = 0; it < 2; ++it) {
      const int idx = it * 256 + tid;
      const int row = idx >> 3, ch = idx & 7;
      const int gch = ch ^ (row & 7);
      __builtin_amdgcn_global_load_lds(
          (gas_t)(const void*)(A + (size_t)(m0 + row) * K + k0 + gch * 8),
          (las_t)(void*)((char*)As + idx * 16), 16, 0, 0);
    }
#pragma unroll
    for (int it = 0; it < 4; ++it) {
      const int idx = it * 256 + tid;
      const int row = idx >> 3, ch = idx & 7;
      const int gch = ch ^ (row & 7);
      __builtin_amdgcn_global_load_lds(
          (gas_t)(const void*)(Bm + (size_t)(n0 + row) * K + k0 + gch * 8),
          (las_t)(void*)((char*)Bs + idx * 16), 16, 0, 0);
    }
    __syncthreads();
#pragma unroll
    for (int kc = 0; kc < 2; ++kc) {
      bf16x8 af[2], bfr[4];
#pragma unroll
      for (int t = 0; t < 2; ++t) {
        const int ra = wm + t * 16 + ln;
        af[t] = *(const bf16x8*)(As + ra * 64 + ((kc * 4 + quad) ^ (ra & 7)) * 8);
      }
#pragma unroll
      for (int t = 0; t < 4; ++t) {
        const int rb = wn + t * 16 + ln;
        bfr[t] = *(const bf16x8*)(Bs + rb * 64 + ((kc * 4 + quad) ^ (rb & 7)) * 8);
      }
#pragma unroll
      for (int mt = 0; mt < 2; ++mt)
#pragma unroll
        for (int nt = 0; nt < 4; ++nt)
          acc[mt][nt] = mfma16(bfr[nt], af[mt], acc[mt][nt]);  // swapped
    }
    __syncthreads();
  }

#pragma unroll
  for (int mt = 0; mt < 2; ++mt) {
#pragma unroll
    for (int nt = 0; nt < 4; ++nt) {
      const int row  = m0 + wm + mt * 16 + ln;        // token
      const int colb = n0 + wn + nt * 16 + quad * 4;  // feature base
      const float4 bv = *(const float4*)(bias + colb);
      float4 ov;
      ov.x = acc[mt][nt][0] + bv.x; ov.y = acc[mt][nt][1] + bv.y;
      ov.z = acc[mt][nt][2] + bv.z; ov.w = acc[mt][nt][3] + bv.w;
      *(float4*)(Cf + (size_t)row * N + colb) = ov;
    }
  }
}

// ---------------- fused causal attention, V == Q (reference bug) -------------
// v7 = v6 (32x32 MFMA, in-register P) with ALL permlane32_swap uses replaced
// by __shfl_xor(x, 32, 64) — v6's correctness failure traced to unverifiable
// permlane semantics (probe couldn't distinguish a third orientation);
// shfl_xor is unambiguous and proven in v5. Structure:
//  * Wave = 32 q-rows (halved K/V LDS fragment traffic vs 16x16).
//  * 4 waves = 2 q-halves x 2 k-halves of 64(q-chunk) x 64(k-tile).
//  * P in registers: swapped QK^T (A=K,B=Q) -> q = lane&31; PV A-fragment
//    built with 4 shfl_xor(32) + 4 selects per 16-k block.
//  * XCD-aware flat swizzle; epilogue cross-wk merge via LDS alias.
// LDS: Ks 8K + Vs 8K + 512B psum -> 16.9 KB.
__global__ __launch_bounds__(256, 4) void attn_kernel(
    const unsigned short* __restrict__ QT,  // [b,h][d=64][s=2048]
    const unsigned short* __restrict__ Kb,  // [b*s][E] row-major, pre-scaled
    unsigned short* __restrict__ Ab) {      // [b*s][E] row-major
  __shared__ __attribute__((aligned(16))) char smem[16384 + 512];
  unsigned short* Ks = (unsigned short*)smem;           // [64 tok][64 d]
  unsigned short* Vs = (unsigned short*)(smem + 8192);  // [64 d][64 tok]
  float* om    = (float*)smem;                          // epilogue alias 16KB
  float* psLds = (float*)(smem + 16384);                // [wq][wk][32 q]

  const int tid = threadIdx.x;
  const int wave = tid >> 6, lane = tid & 63;
  const int wq = wave >> 1, wk = wave & 1;
  const int lq = lane & 31, hi = lane >> 5;

  // XCD-aware block swizzle: flat id -> (bx, h, b) with all 16 bx of one
  // (b,h) on one XCD (assumes XCD = flat_id % 8 round-robin).
  const int fp = (int)blockIdx.x + ((int)blockIdx.y << 4) + ((int)blockIdx.z << 8);
  const int xr = fp & 7, sl = fp >> 3;
  const int bx = sl & 15;
  const int g  = ((sl >> 4) << 3) + xr;   // 0..63
  const int h = g & 15, b = g >> 4;

  const size_t hoff  = ((size_t)b * PS) * PE + (size_t)h * PD;
  const size_t hofft = ((size_t)(b * PH + h) * PD) * PS;

  for (int pass = 0; pass < 2; ++pass) {
    const int qc = pass ? bx : 31 - bx;     // paired chunks: uniform 33 iters
    const int qw0 = qc * 64 + wq * 32;
    const int qg = qw0 + lq;                // this lane's q (P col)

    // Q fragments (B-operand): col=lane&31=q, d = 16s4 + 8hi + j
    bf16x8 qfr[4];
#pragma unroll
    for (int s4 = 0; s4 < 4; ++s4) {
      union { unsigned short u[8]; bf16x8 v; } t;
#pragma unroll
      for (int j = 0; j < 8; ++j)
        t.u[j] = QT[hofft + (size_t)(16 * s4 + 8 * hi + j) * PS + qg];
      qfr[s4] = t.v;
    }

    f32x16 o0, o1;
#pragma unroll
    for (int i = 0; i < 16; ++i) { o0[i] = 0.f; o1[i] = 0.f; }
    float psum = 0.f;

    const int ktend = qc + 1;
    for (int kt = 0; kt < ktend; ++kt) {
      const int k0 = kt * 64;

      // stage K (rows=tokens) and V (rows=d) with XOR chunk swizzle
#pragma unroll
      for (int it = 0; it < 2; ++it) {
        const int idx = it * 256 + tid;
        const int row = idx >> 3, ch = idx & 7;
        const int gch = ch ^ (row & 7);
        __builtin_amdgcn_global_load_lds(
            (gas_t)(const void*)(Kb + hoff + (size_t)(k0 + row) * PE + gch * 8),
            (las_t)(void*)((char*)Ks + idx * 16), 16, 0, 0);
        __builtin_amdgcn_global_load_lds(
            (gas_t)(const void*)(QT + hofft + (size_t)row * PS + k0 + gch * 8),
            (las_t)(void*)((char*)Vs + idx * 16), 16, 0, 0);
      }
      __syncthreads();

      const int kbw = k0 + wk * 32;          // this wave's k-half base
      if (kbw <= qw0 + 31) {                 // skip fully-masked half-tiles
        // QK^T: D[k-row][q-col], A = K rows, B = Q
        f32x16 sacc;
#pragma unroll
        for (int i = 0; i < 16; ++i) sacc[i] = 0.f;
        const int krow = wk * 32 + lq;
        __builtin_amdgcn_s_setprio(1);
#pragma unroll
        for (int s4 = 0; s4 < 4; ++s4) {
          const int ch = ((2 * s4 + hi) ^ (krow & 7)) * 8;
          bf16x8 kf = *(const bf16x8*)(Ks + krow * 64 + ch);
          sacc = mfma32(kf, qfr[s4], sacc);
        }
        __builtin_amdgcn_s_setprio(0);

        const bool edge = (kbw + 31) > qw0;
        const int kb4 = kbw + 4 * hi;
#pragma unroll
        for (int sb = 0; sb < 2; ++sb) {
          // exp + mask + psum for regs 8sb..8sb+7
          float pv[8];
#pragma unroll
          for (int i = 0; i < 8; ++i) {
            float e = __builtin_amdgcn_exp2f(sacc[8 * sb + i]);
            if (edge) {
              const int kg = kb4 + (i & 3) + 8 * (2 * sb + (i >> 2));
              e = (kg <= qg) ? e : 0.f;
            }
            pv[i] = e;
          }
          psum += ((pv[0] + pv[1]) + (pv[2] + pv[3])) +
                  ((pv[4] + pv[5]) + (pv[6] + pv[7]));
          // pack to bf16 pairs.
          // lane(hi=0) holds k16 {0..3, 8..11}: c0=(0,1) c1=(2,3) c2=(8,9) c3=(10,11)
          // lane(hi=1) holds k16 {4..7,12..15}: c0=(4,5) c1=(6,7) c2=(12,13) c3=(14,15)
          // pf needs k16 = 8*hi + (0..7): lo lanes {c0,c1,partner c0,c1},
          // hi lanes {partner c2,c3, own c2,c3}. Exchange via shfl_xor(32).
          union { __hip_bfloat162 h2; unsigned int u; } c0, c1, c2, c3;
          c0.h2 = __float22bfloat162_rn(float2{pv[0], pv[1]});
          c1.h2 = __float22bfloat162_rn(float2{pv[2], pv[3]});
          c2.h2 = __float22bfloat162_rn(float2{pv[4], pv[5]});
          c3.h2 = __float22bfloat162_rn(float2{pv[6], pv[7]});
          const unsigned int e0 = (unsigned int)__shfl_xor((int)c0.u, 32, 64);
          const unsigned int e1 = (unsigned int)__shfl_xor((int)c1.u, 32, 64);
          const unsigned int e2 = (unsigned int)__shfl_xor((int)c2.u, 32, 64);
          const unsigned int e3 = (unsigned int)__shfl_xor((int)c3.u, 32, 64);
          union { unsigned int u[4]; bf16x8 v; } pf;
          pf.u[0] = hi ? e2 : c0.u;
          pf.u[1] = hi ? e3 : c1.u;
          pf.u[2] = hi ? c2.u : e0;
          pf.u[3] = hi ? c3.u : e1;

          // PV: o[dblk] += P(32q x 16k) * V(16k x 32d)
          const int chv = wk * 4 + 2 * sb + hi;
          __builtin_amdgcn_s_setprio(1);
          {
            const int r0 = lq;
            bf16x8 vf0 = *(const bf16x8*)(Vs + r0 * 64 + ((chv ^ (r0 & 7)) * 8));
            o0 = mfma32(pf.v, vf0, o0);
            const int r1 = 32 + lq;
            bf16x8 vf1 = *(const bf16x8*)(Vs + r1 * 64 + ((chv ^ (r1 & 7)) * 8));
            o1 = mfma32(pf.v, vf1, o1);
          }
          __builtin_amdgcn_s_setprio(0);
        }
      }
      __syncthreads();
    }

    // ---- epilogue: cross-hi psum, cross-wk o merge, normalize, store ----
    psum += __shfl_xor(psum, 32, 64);   // full k-half sum for q = lq
    if (lane < 32) psLds[(wq * 2 + wk) * 32 + lane] = psum;
    if (wk == 1) {
#pragma unroll
      for (int c = 0; c < 8; ++c) {
        const int base = (c & 3) * 4;
        float4 v;
        if (c < 4) v = float4{o0[base], o0[base + 1], o0[base + 2], o0[base + 3]};
        else       v = float4{o1[base], o1[base + 1], o1[base + 2], o1[base + 3]};
        *(float4*)(om + ((wq * 8 + c) * 64 + lane) * 4) = v;
      }
    }
    __syncthreads();
    if (wk == 0) {
#pragma unroll
      for (int c = 0; c < 8; ++c) {
        const float4 v = *(const float4*)(om + ((wq * 8 + c) * 64 + lane) * 4);
        const int base = (c & 3) * 4;
        if (c < 4) { o0[base] += v.x; o0[base+1] += v.y; o0[base+2] += v.z; o0[base+3] += v.w; }
        else       { o1[base] += v.x; o1[base+1] += v.y; o1[base+2] += v.z; o1[base+3] += v.w; }
      }
#pragma unroll
      for (int reg = 0; reg < 16; ++reg) {
        const int qrow = (reg & 3) + 8 * (reg >> 2) + 4 * hi;
        const float tot = psLds[(wq * 2 + 0) * 32 + qrow] +
                          psLds[(wq * 2 + 1) * 32 + qrow];
        const float inv = 1.f / tot;
        const size_t rb = hoff + (size_t)(qw0 + qrow) * PE;
        Ab[rb + lq]      = f2bf(o0[reg] * inv);
        Ab[rb + 32 + lq] = f2bf(o1[reg] * inv);
      }
    }
    __syncthreads();  // protect smem (om alias) before next pass staging
  }
}

// ---------------------------------------------------------------------------
extern "C" void kernel_launch(void* const* d_in, const int* in_sizes, int n_in,
                              void* d_out, int out_size, void* d_ws, size_t ws_size,
                              hipStream_t stream) {
  (void)in_sizes; (void)n_in; (void)out_size; (void)ws_size;
  const float* x  = (const float*)d_in[0];
  const float* Wk = (const float*)d_in[1];
  const float* Wq = (const float*)d_in[2];
  // d_in[3] = Wv : dead in the reference (V = Q bug) — never touched.
  const float* Wo = (const float*)d_in[4];
  const float* bo = (const float*)d_in[5];
  float* out = (float*)d_out;

  char* ws = (char*)d_ws;
  unsigned short* xb  = (unsigned short*)(ws);                       // 16 MiB
  unsigned short* wkb = (unsigned short*)(ws + (16u << 20));         //  2 MiB
  unsigned short* wqb = (unsigned short*)(ws + (18u << 20));         //  2 MiB
  unsigned short* wob = (unsigned short*)(ws + (20u << 20));         //  2 MiB
  unsigned short* QT  = (unsigned short*)(ws + (22u << 20));         // 16 MiB
  unsigned short* Kb  = (unsigned short*)(ws + (38u << 20));         // 16 MiB
  unsigned short* Ab  = xb;  // alias: xb dead after gemm_qknt

  const int M = PB * PS;  // 8192

  // 1) fp32 -> bf16
  cvt_kernel<<<dim3(CVT_BLOCKS), dim3(256), 0, stream>>>(
      x, Wk, Wq, Wo, xb, wkb, wqb, wob);

  // 2) Q = x Wq^T (z=0, -> QT transposed), K = x Wk^T (z=1, -> row-major,
  //    scaled). 1024 blocks = 4/CU.
  gemm_qknt<<<dim3(PE / 128, M / 128, 2), dim3(256), 0, stream>>>(
      xb, wqb, wkb, QT, Kb);

  // 3) causal attention (V = Q) — 32x32 MFMA, in-register P, 1024 blocks
  attn_kernel<<<dim3(16, 16, 4), dim3(256), 0, stream>>>(QT, Kb, Ab);

  // 4) out = attn Wo^T + bo (fp32) — 64x128 tiles, 1024 blocks = 4/CU
  gemm_out<<<dim3(PE / 128, M / 64), dim3(256), 0, stream>>>(
      Ab, wob, bo, out);
}